// Round 1
// baseline (229.453 us; speedup 1.0000x reference)
//
#include <hip/hip_runtime.h>
#include <math.h>

// LDR toep_corner layer via 5-pass FFT identity chain.
// out[j,b] = Re ifft( sum_{i,s} fft(G_ijs) . fft( D . fft( fft(D.H_ijs) . ifft(Dbar.x_ib) ) ) )
// D_k = exp(i*pi*k/N).  All FFTs are N=4096 complex, done in LDS (Stockham radix-2).

#define NFFT   4096
#define LOG2N  12
#define NT     256
#define CIN    4
#define COUT   4
#define RANK   4
#define BATCH  32
#define PI_F   3.14159265358979323846f

__device__ __forceinline__ float2 cmul(float2 a, float2 b) {
    return make_float2(a.x*b.x - a.y*b.y, a.x*b.y + a.y*b.x);
}
__device__ __forceinline__ float2 cadd(float2 a, float2 b) { return make_float2(a.x+b.x, a.y+b.y); }
__device__ __forceinline__ float2 csub(float2 a, float2 b) { return make_float2(a.x-b.x, a.y-b.y); }

// In-LDS Stockham radix-2 FFT, N=4096, NT=256 threads.
// Data starts in b0; after 12 stages (even count) the result is back in b0.
// sign = -1 forward (numpy convention), +1 inverse (caller applies 1/N).
// Caller must __syncthreads() after filling b0 before calling.
__device__ void fft4096(float2* b0, float2* b1, int tid, float sign) {
    float2* src = b0;
    float2* dst = b1;
    int nn = NFFT;
    int ls = 0;  // log2(stride)
    for (int stage = 0; stage < LOG2N; ++stage) {
        int m = nn >> 1;
        int s = 1 << ls;
        float theta0 = sign * 2.0f * PI_F / (float)nn;
        #pragma unroll
        for (int u = 0; u < (NFFT / 2) / NT; ++u) {
            int idx = tid + u * NT;
            int p = idx >> ls;        // [0, m)
            int q = idx & (s - 1);    // [0, s)
            float sn, cs;
            __sincosf(theta0 * (float)p, &sn, &cs);
            float2 wp = make_float2(cs, sn);
            float2 A = src[q + (p << ls)];
            float2 B = src[q + ((p + m) << ls)];
            dst[q + ((2 * p) << ls)]     = cadd(A, B);
            dst[q + ((2 * p + 1) << ls)] = cmul(csub(A, B), wp);
        }
        __syncthreads();
        nn = m;
        ++ls;
        float2* t = src; src = dst; dst = t;
    }
}

// Kernel A: blockIdx 0..63 -> Hf rows, 64..127 -> Gf rows, 128..255 -> Xf rows.
__global__ __launch_bounds__(NT) void ldr_precompute(
    const float* __restrict__ x, const float* __restrict__ G, const float* __restrict__ H,
    float2* __restrict__ Hf, float2* __restrict__ Gf, float2* __restrict__ Xf)
{
    __shared__ float2 b0[NFFT];
    __shared__ float2 b1[NFFT];
    const int tid = threadIdx.x;
    const int bid = blockIdx.x;
    const float pi_n = PI_F / (float)NFFT;

    if (bid < 64) {
        // Hf[row] = fft(D * H[row])
        const float* h = H + (size_t)bid * NFFT;
        for (int e = tid; e < NFFT; e += NT) {
            float sn, cs; __sincosf(pi_n * (float)e, &sn, &cs);
            float v = h[e];
            b0[e] = make_float2(cs * v, sn * v);
        }
        __syncthreads();
        fft4096(b0, b1, tid, -1.0f);
        float2* o = Hf + (size_t)bid * NFFT;
        for (int e = tid; e < NFFT; e += NT) o[e] = b0[e];
    } else if (bid < 128) {
        // Gf[row] = fft(G[row])
        const int row = bid - 64;
        const float* g = G + (size_t)row * NFFT;
        for (int e = tid; e < NFFT; e += NT) b0[e] = make_float2(g[e], 0.0f);
        __syncthreads();
        fft4096(b0, b1, tid, -1.0f);
        float2* o = Gf + (size_t)row * NFFT;
        for (int e = tid; e < NFFT; e += NT) o[e] = b0[e];
    } else {
        // Xf[row] = ifft(conj(D) * x[row]),  row = i*BATCH + b
        const int row = bid - 128;
        const float* xp = x + (size_t)row * NFFT;
        for (int e = tid; e < NFFT; e += NT) {
            float sn, cs; __sincosf(pi_n * (float)e, &sn, &cs);
            float v = xp[e];
            b0[e] = make_float2(cs * v, -sn * v);
        }
        __syncthreads();
        fft4096(b0, b1, tid, +1.0f);
        const float invn = 1.0f / (float)NFFT;
        float2* o = Xf + (size_t)row * NFFT;
        for (int e = tid; e < NFFT; e += NT)
            o[e] = make_float2(b0[e].x * invn, b0[e].y * invn);
    }
}

// Kernel B: one wg per (i,j,b): P[i,j,b] = sum_s Gf[ijs] . fft(D . fft(Hf[ijs] . Xf[ib]))
__global__ __launch_bounds__(NT) void ldr_middle(
    const float2* __restrict__ Hf, const float2* __restrict__ Xf,
    const float2* __restrict__ Gf, float2* __restrict__ P)
{
    __shared__ float2 b0[NFFT];
    __shared__ float2 b1[NFFT];
    const int tid = threadIdx.x;
    const int bid = blockIdx.x;          // (i*COUT + j)*BATCH + b
    const int b  = bid % BATCH;
    const int ij = bid / BATCH;          // i*COUT + j
    const int i  = ij / COUT;
    const float2* xrow = Xf + ((size_t)(i * BATCH + b)) * NFFT;
    const float pi_n = PI_F / (float)NFFT;

    float2 acc[16];
    #pragma unroll
    for (int k = 0; k < 16; ++k) acc[k] = make_float2(0.0f, 0.0f);

    for (int s = 0; s < RANK; ++s) {
        const float2* hrow = Hf + ((size_t)(ij * RANK + s)) * NFFT;
        const float2* grow = Gf + ((size_t)(ij * RANK + s)) * NFFT;
        for (int e = tid; e < NFFT; e += NT) b0[e] = cmul(hrow[e], xrow[e]);
        __syncthreads();
        fft4096(b0, b1, tid, -1.0f);
        // multiply by D (each thread touches only elements it owns)
        for (int e = tid; e < NFFT; e += NT) {
            float sn, cs; __sincosf(pi_n * (float)e, &sn, &cs);
            b0[e] = cmul(make_float2(cs, sn), b0[e]);
        }
        __syncthreads();
        fft4096(b0, b1, tid, -1.0f);
        #pragma unroll
        for (int k = 0; k < 16; ++k) {
            int e = tid + k * NT;
            acc[k] = cadd(acc[k], cmul(grow[e], b0[e]));
        }
        __syncthreads();
    }
    float2* prow = P + (size_t)bid * NFFT;
    #pragma unroll
    for (int k = 0; k < 16; ++k) prow[tid + k * NT] = acc[k];
}

// Kernel C: one wg per (j,b): out[j,b] = Re ifft( sum_i P[i,j,b] )
__global__ __launch_bounds__(NT) void ldr_final(
    const float2* __restrict__ P, float* __restrict__ out)
{
    __shared__ float2 b0[NFFT];
    __shared__ float2 b1[NFFT];
    const int tid = threadIdx.x;
    const int bid = blockIdx.x;          // j*BATCH + b
    const int b = bid % BATCH;
    const int j = bid / BATCH;
    for (int e = tid; e < NFFT; e += NT) {
        float2 a = make_float2(0.0f, 0.0f);
        #pragma unroll
        for (int i = 0; i < CIN; ++i)
            a = cadd(a, P[((size_t)((i * COUT + j) * BATCH + b)) * NFFT + e]);
        b0[e] = a;
    }
    __syncthreads();
    fft4096(b0, b1, tid, +1.0f);
    const float invn = 1.0f / (float)NFFT;
    float* orow = out + (size_t)bid * NFFT;   // (COUT,B,N) row-major: bid = j*BATCH+b
    for (int e = tid; e < NFFT; e += NT) orow[e] = b0[e].x * invn;
}

// Fallback: fused middle+final (only needs Hf/Gf/Xf = 8 MB of ws).
__global__ __launch_bounds__(NT) void ldr_fused(
    const float2* __restrict__ Hf, const float2* __restrict__ Xf,
    const float2* __restrict__ Gf, float* __restrict__ out)
{
    __shared__ float2 b0[NFFT];
    __shared__ float2 b1[NFFT];
    const int tid = threadIdx.x;
    const int bid = blockIdx.x;          // j*BATCH + b
    const int b = bid % BATCH;
    const int j = bid / BATCH;
    const float pi_n = PI_F / (float)NFFT;

    float2 acc[16];
    #pragma unroll
    for (int k = 0; k < 16; ++k) acc[k] = make_float2(0.0f, 0.0f);

    for (int i = 0; i < CIN; ++i) {
        const float2* xrow = Xf + ((size_t)(i * BATCH + b)) * NFFT;
        for (int s = 0; s < RANK; ++s) {
            const int rr = (i * COUT + j) * RANK + s;
            const float2* hrow = Hf + (size_t)rr * NFFT;
            const float2* grow = Gf + (size_t)rr * NFFT;
            for (int e = tid; e < NFFT; e += NT) b0[e] = cmul(hrow[e], xrow[e]);
            __syncthreads();
            fft4096(b0, b1, tid, -1.0f);
            for (int e = tid; e < NFFT; e += NT) {
                float sn, cs; __sincosf(pi_n * (float)e, &sn, &cs);
                b0[e] = cmul(make_float2(cs, sn), b0[e]);
            }
            __syncthreads();
            fft4096(b0, b1, tid, -1.0f);
            #pragma unroll
            for (int k = 0; k < 16; ++k) {
                int e = tid + k * NT;
                acc[k] = cadd(acc[k], cmul(grow[e], b0[e]));
            }
            __syncthreads();
        }
    }
    #pragma unroll
    for (int k = 0; k < 16; ++k) b0[tid + k * NT] = acc[k];
    __syncthreads();
    fft4096(b0, b1, tid, +1.0f);
    const float invn = 1.0f / (float)NFFT;
    float* orow = out + (size_t)bid * NFFT;
    for (int e = tid; e < NFFT; e += NT) orow[e] = b0[e].x * invn;
}

extern "C" void kernel_launch(void* const* d_in, const int* in_sizes, int n_in,
                              void* d_out, int out_size, void* d_ws, size_t ws_size,
                              hipStream_t stream) {
    const float* x = (const float*)d_in[0];   // (CIN, B, N)
    const float* G = (const float*)d_in[1];   // (CIN, COUT, R, N)
    const float* H = (const float*)d_in[2];   // (CIN, COUT, R, N)
    float* out = (float*)d_out;               // (COUT, B, N)

    float2* Hf = (float2*)d_ws;                       // 64  rows
    float2* Gf = Hf + (size_t)64 * NFFT;              // 64  rows
    float2* Xf = Gf + (size_t)64 * NFFT;              // 128 rows
    float2* P  = Xf + (size_t)128 * NFFT;             // 512 rows

    const size_t need_full = (size_t)(64 + 64 + 128 + 512) * NFFT * sizeof(float2); // 24 MB

    ldr_precompute<<<256, NT, 0, stream>>>(x, G, H, Hf, Gf, Xf);
    if (ws_size >= need_full) {
        ldr_middle<<<CIN * COUT * BATCH, NT, 0, stream>>>(Hf, Xf, Gf, P);
        ldr_final<<<COUT * BATCH, NT, 0, stream>>>(P, out);
    } else {
        ldr_fused<<<COUT * BATCH, NT, 0, stream>>>(Hf, Xf, Gf, out);
    }
}

// Round 2
// 151.644 us; speedup vs baseline: 1.5131x; 1.5131x over previous
//
#include <hip/hip_runtime.h>
#include <math.h>

// LDR toep_corner via 5-pass FFT chain, radix-16 registerized FFT (4096 = 16^3).
// out[j,b] = Re ifft( sum_{i,s} Gf_ijs . fft( D . fft( Hf_ijs . Xf_ib ) ) )
// Hf = fft(D.H), Xf = ifft(conj(D).x), Gf = fft(G), D_k = exp(i*pi*k/N).

#define NFFT  4096
#define NT    256
#define CIN   4
#define COUT  4
#define RANK  4
#define BATCH 32
#define PI_F  3.14159265358979323846f

__device__ __forceinline__ float2 cmul(float2 a, float2 b) {
    return make_float2(a.x*b.x - a.y*b.y, a.x*b.y + a.y*b.x);
}
__device__ __forceinline__ float2 cadd(float2 a, float2 b){ return make_float2(a.x+b.x, a.y+b.y); }
__device__ __forceinline__ float2 csub(float2 a, float2 b){ return make_float2(a.x-b.x, a.y-b.y); }

// LDS bank swizzle: keeps bits 4..11, XORs low 4 with bits 4..7.
// All three access patterns (stride-256 reads, 16tid+k writes, q+256p+16k writes)
// then hit each bank-pair with exactly 4 of 64 lanes = the b64 floor (conflict-free).
__device__ __forceinline__ int SW(int e){ return e ^ ((e >> 4) & 15); }

// 16-point DFT in registers, natural order in/out: v[k] = sum_r v_in[r] e^{SIGN*2pi*i*rk/16}
template<int SIGN>
__device__ __forceinline__ void dft16(float2 v[16]) {
    const float sgn = (float)SIGN;
    const float C8 = 0.923879532511287f, S8 = 0.382683432365090f, H2 = 0.707106781186548f;
    const float2 w1 = make_float2( C8,  sgn*S8);
    const float2 w2 = make_float2( H2,  sgn*H2);
    const float2 w3 = make_float2( S8,  sgn*C8);
    const float2 w4 = make_float2(0.f,  sgn);
    const float2 w6 = make_float2(-H2,  sgn*H2);
    const float2 w9 = make_float2(-C8, -sgn*S8);
    float2 t[16];
    #pragma unroll
    for (int p = 0; p < 4; ++p) {
        float2 a0 = v[p], a1 = v[p+4], a2 = v[p+8], a3 = v[p+12];
        float2 b0 = cadd(a0,a2), b1 = csub(a0,a2), b2 = cadd(a1,a3), b3 = csub(a1,a3);
        float2 ib3 = make_float2(-sgn*b3.y, sgn*b3.x);   // SIGN*i*b3
        float2 X0 = cadd(b0,b2), X2c = csub(b0,b2);
        float2 X1 = cadd(b1,ib3), X3 = csub(b1,ib3);
        if (p == 1) { X1 = cmul(X1,w1); X2c = cmul(X2c,w2); X3 = cmul(X3,w3); }
        else if (p == 2) { X1 = cmul(X1,w2); X2c = cmul(X2c,w4); X3 = cmul(X3,w6); }
        else if (p == 3) { X1 = cmul(X1,w3); X2c = cmul(X2c,w6); X3 = cmul(X3,w9); }
        t[4*p+0]=X0; t[4*p+1]=X1; t[4*p+2]=X2c; t[4*p+3]=X3;
    }
    #pragma unroll
    for (int q = 0; q < 4; ++q) {
        float2 a0 = t[q], a1 = t[q+4], a2 = t[q+8], a3 = t[q+12];
        float2 b0 = cadd(a0,a2), b1 = csub(a0,a2), b2 = cadd(a1,a3), b3 = csub(a1,a3);
        float2 ib3 = make_float2(-sgn*b3.y, sgn*b3.x);
        v[q+0]  = cadd(b0,b2);
        v[q+8]  = csub(b0,b2);
        v[q+4]  = cadd(b1,ib3);
        v[q+12] = csub(b1,ib3);
    }
}

// v[k] *= e^{i*k*ang} (ang carries the sign), incremental powers.
__device__ __forceinline__ void twiddle16(float2 v[16], float ang) {
    float sn, cs; __sincosf(ang, &sn, &cs);
    float2 w = make_float2(cs, sn), t = w;
    v[1] = cmul(v[1], t);
    #pragma unroll
    for (int k = 2; k < 16; ++k) { t = cmul(t, w); v[k] = cmul(v[k], t); }
}

// Stockham radix-16, 3 stages. Input: v[r] = x[tid + 256r]. Output: v[k] = X[tid + 256k].
// Entry assumes lds free to write; exits with trailing barrier (lds free again).
template<int SIGN>
__device__ void fft4096_r16(float2 v[16], float2* lds, int tid) {
    // Stage A: nn=4096, s=1, p=tid
    dft16<SIGN>(v);
    twiddle16(v, (float)SIGN * 2.0f * PI_F * (float)tid / 4096.0f);
    #pragma unroll
    for (int k = 0; k < 16; ++k) lds[SW(16*tid + k)] = v[k];
    __syncthreads();
    // Stage B: nn=256, s=16, p=tid>>4, q=tid&15
    #pragma unroll
    for (int r = 0; r < 16; ++r) v[r] = lds[SW(tid + 256*r)];
    dft16<SIGN>(v);
    twiddle16(v, (float)SIGN * 2.0f * PI_F * (float)(tid >> 4) / 256.0f);
    __syncthreads();                       // in-place: all reads before any write
    {
        const int q = tid & 15, p = tid >> 4;
        #pragma unroll
        for (int k = 0; k < 16; ++k) lds[SW(q + 256*p + 16*k)] = v[k];
    }
    __syncthreads();
    // Stage C: nn=16, s=256, p=0 (no twiddle)
    #pragma unroll
    for (int r = 0; r < 16; ++r) v[r] = lds[SW(tid + 256*r)];
    dft16<SIGN>(v);
    __syncthreads();                       // lds reusable by caller
}

// ---- Kernel A: precompute Hf (64 rows), Gf (64 rows), Xf (128 rows) ----
__global__ __launch_bounds__(NT, 2) void ldr_pre_k(
    const float* __restrict__ x, const float* __restrict__ G, const float* __restrict__ H,
    float2* __restrict__ Hf, float2* __restrict__ Gf, float2* __restrict__ Xf)
{
    __shared__ float2 lds[NFFT];
    const int tid = threadIdx.x;
    const int bid = blockIdx.x;
    float2 v[16];
    if (bid < 64) {
        const float* h = H + (size_t)bid * NFFT;
        float sn, cs; __sincosf(PI_F * (float)tid / (float)NFFT, &sn, &cs);
        float2 d = make_float2(cs, sn);
        const float2 dstep = make_float2(0.980785280403230449f, 0.195090322016128268f); // e^{i*pi/16}
        #pragma unroll
        for (int k = 0; k < 16; ++k) {
            float hv = h[tid + 256*k];
            v[k] = make_float2(d.x*hv, d.y*hv);
            d = cmul(d, dstep);
        }
        fft4096_r16<-1>(v, lds, tid);
        float2* o = Hf + (size_t)bid * NFFT;
        #pragma unroll
        for (int k = 0; k < 16; ++k) o[tid + 256*k] = v[k];
    } else if (bid < 128) {
        const int row = bid - 64;
        const float* g = G + (size_t)row * NFFT;
        #pragma unroll
        for (int k = 0; k < 16; ++k) v[k] = make_float2(g[tid + 256*k], 0.0f);
        fft4096_r16<-1>(v, lds, tid);
        float2* o = Gf + (size_t)row * NFFT;
        #pragma unroll
        for (int k = 0; k < 16; ++k) o[tid + 256*k] = v[k];
    } else {
        const int row = bid - 128;
        const float* xp = x + (size_t)row * NFFT;
        float sn, cs; __sincosf(PI_F * (float)tid / (float)NFFT, &sn, &cs);
        float2 d = make_float2(cs, -sn);                                                 // conj(D)
        const float2 dstep = make_float2(0.980785280403230449f, -0.195090322016128268f);
        #pragma unroll
        for (int k = 0; k < 16; ++k) {
            float xv = xp[tid + 256*k];
            v[k] = make_float2(d.x*xv, d.y*xv);
            d = cmul(d, dstep);
        }
        fft4096_r16<1>(v, lds, tid);
        const float invn = 1.0f / (float)NFFT;
        float2* o = Xf + (size_t)row * NFFT;
        #pragma unroll
        for (int k = 0; k < 16; ++k) o[tid + 256*k] = make_float2(v[k].x*invn, v[k].y*invn);
    }
}

// ---- Kernel B: middle. NS = ranks per workgroup; grid = 512 * (RANK/NS).
// P row index = ((ij*BATCH+b)*(RANK/NS) + sg); partial over the wg's NS ranks.
template<int NS>
__global__ __launch_bounds__(NT, (NS >= 4) ? 2 : 4) void ldr_middle_k(
    const float2* __restrict__ Hf, const float2* __restrict__ Xf,
    const float2* __restrict__ Gf, float2* __restrict__ P)
{
    constexpr int SS = RANK / NS;
    __shared__ float2 lds[NFFT];
    const int tid  = threadIdx.x;
    const int bid  = blockIdx.x;
    const int sg   = bid % SS;
    const int rest = bid / SS;            // ij*BATCH + b
    const int b    = rest % BATCH;
    const int ij   = rest / BATCH;
    const int i    = ij / COUT;
    const float2* xrow = Xf + (size_t)(i*BATCH + b) * NFFT;

    float2 acc[16];
    #pragma unroll
    for (int k = 0; k < 16; ++k) acc[k] = make_float2(0.0f, 0.0f);

    for (int ss = 0; ss < NS; ++ss) {
        const int s = sg*NS + ss;
        const float2* hrow = Hf + (size_t)(ij*RANK + s) * NFFT;
        const float2* grow = Gf + (size_t)(ij*RANK + s) * NFFT;
        float2 v[16];
        #pragma unroll
        for (int k = 0; k < 16; ++k) {
            const int e = tid + 256*k;
            v[k] = cmul(hrow[e], xrow[e]);
        }
        fft4096_r16<-1>(v, lds, tid);
        // multiply by D in registers: elem e = tid + 256k, D_e = e^{i*pi*e/N}
        float sn, cs; __sincosf(PI_F * (float)tid / (float)NFFT, &sn, &cs);
        float2 d = make_float2(cs, sn);
        const float2 dstep = make_float2(0.980785280403230449f, 0.195090322016128268f);
        #pragma unroll
        for (int k = 0; k < 16; ++k) { v[k] = cmul(v[k], d); d = cmul(d, dstep); }
        fft4096_r16<-1>(v, lds, tid);
        #pragma unroll
        for (int k = 0; k < 16; ++k) {
            const int e = tid + 256*k;
            acc[k] = cadd(acc[k], cmul(grow[e], v[k]));
        }
    }
    float2* prow = P + (size_t)bid * NFFT;
    #pragma unroll
    for (int k = 0; k < 16; ++k) prow[tid + 256*k] = acc[k];
}

// ---- Kernel C: final. out[j,b] = Re ifft( sum_{i,sg} P ) / N ----
__global__ __launch_bounds__(NT, 2) void ldr_final_k(
    const float2* __restrict__ P, float* __restrict__ out, int ssplit)
{
    __shared__ float2 lds[NFFT];
    const int tid = threadIdx.x;
    const int bid = blockIdx.x;          // j*BATCH + b
    const int b = bid % BATCH;
    const int j = bid / BATCH;
    float2 v[16];
    #pragma unroll
    for (int k = 0; k < 16; ++k) v[k] = make_float2(0.0f, 0.0f);
    for (int i = 0; i < CIN; ++i) {
        const float2* base = P + (size_t)(((i*COUT + j)*BATCH + b) * ssplit) * NFFT;
        for (int sg = 0; sg < ssplit; ++sg) {
            const float2* row = base + (size_t)sg * NFFT;
            #pragma unroll
            for (int k = 0; k < 16; ++k) v[k] = cadd(v[k], row[tid + 256*k]);
        }
    }
    fft4096_r16<1>(v, lds, tid);
    const float invn = 1.0f / (float)NFFT;
    float* orow = out + (size_t)bid * NFFT;
    #pragma unroll
    for (int k = 0; k < 16; ++k) orow[tid + 256*k] = v[k].x * invn;
}

extern "C" void kernel_launch(void* const* d_in, const int* in_sizes, int n_in,
                              void* d_out, int out_size, void* d_ws, size_t ws_size,
                              hipStream_t stream) {
    const float* x = (const float*)d_in[0];   // (CIN, B, N)
    const float* G = (const float*)d_in[1];   // (CIN, COUT, R, N)
    const float* H = (const float*)d_in[2];   // (CIN, COUT, R, N)
    float* out = (float*)d_out;               // (COUT, B, N)

    float2* Hf = (float2*)d_ws;                    // 64 rows
    float2* Gf = Hf + (size_t)64 * NFFT;           // 64 rows
    float2* Xf = Gf + (size_t)64 * NFFT;           // 128 rows
    float2* P  = Xf + (size_t)128 * NFFT;          // 512 * ssplit rows

    const size_t rowb = (size_t)NFFT * sizeof(float2);   // 32 KB
    int ssplit;
    if      (ws_size >= (256 + 2048) * rowb) ssplit = 4; // 72 MB
    else if (ws_size >= (256 + 1024) * rowb) ssplit = 2; // 40 MB
    else                                     ssplit = 1; // 24 MB (round-1 proven)

    ldr_pre_k<<<256, NT, 0, stream>>>(x, G, H, Hf, Gf, Xf);
    if      (ssplit == 4) ldr_middle_k<1><<<2048, NT, 0, stream>>>(Hf, Xf, Gf, P);
    else if (ssplit == 2) ldr_middle_k<2><<<1024, NT, 0, stream>>>(Hf, Xf, Gf, P);
    else                  ldr_middle_k<4><<< 512, NT, 0, stream>>>(Hf, Xf, Gf, P);
    ldr_final_k<<<COUT * BATCH, NT, 0, stream>>>(P, out, ssplit);
}